// Round 3
// baseline (187.193 us; speedup 1.0000x reference)
//
#include <hip/hip_runtime.h>
#include <cstdint>

#define T_TOK 4096
#define KDIM 2048
#define NE 64
#define NP 2
#define EE 32
#define CAP 160
#define NKC 8
#define KCHUNK 256
#define KSUB 128
#define COMB_ELEMS 41943040ull /* 8192 * 5120 */
#define OUT_ELEMS 83886081ull  /* 1 + 2*COMB */

// ---------------- GEMM: logits partials, K split into 8 chunks ----------------
__global__ __launch_bounds__(256) void k_gemm(const float* __restrict__ x,
                                              const float* __restrict__ W,
                                              float* __restrict__ part) {
  __shared__ float wt[KSUB][NE + 1];  // [k][e], pad -> conflict-free
  const int tid = threadIdx.x;
  const int rb = blockIdx.x & 127;   // 128 row-blocks of 32 rows
  const int kc = blockIdx.x >> 7;    // 8 k-chunks of 256
  const int lane = tid & 63;         // lane = global expert e
  const int rg = __builtin_amdgcn_readfirstlane(tid >> 6);
  const int r0 = rb * 32 + rg * 8;
  float acc[8];
#pragma unroll
  for (int i = 0; i < 8; ++i) acc[i] = 0.f;

  for (int sub = 0; sub < 2; ++sub) {
    const int kbase = kc * KCHUNK + sub * KSUB;
    __syncthreads();
#pragma unroll
    for (int it = 0; it < 32; ++it) {  // 64e x 128k cooperative load, transposed
      int idx = tid + it * 256;
      int e = idx >> 7;
      int k = idx & 127;
      wt[k][e] = W[e * KDIM + kbase + k];
    }
    __syncthreads();
    for (int k = 0; k < KSUB; k += 4) {
      float w0 = wt[k][lane], w1 = wt[k + 1][lane];
      float w2 = wt[k + 2][lane], w3 = wt[k + 3][lane];
#pragma unroll
      for (int i = 0; i < 8; ++i) {
        // wave-uniform address -> s_load_dwordx4
        const float4 xv = *reinterpret_cast<const float4*>(
            &x[(size_t)(r0 + i) * KDIM + kbase + k]);
        acc[i] = fmaf(xv.w, w3, fmaf(xv.z, w2, fmaf(xv.y, w1, fmaf(xv.x, w0, acc[i]))));
      }
    }
  }
#pragma unroll
  for (int i = 0; i < 8; ++i)
    part[((size_t)kc * T_TOK + (r0 + i)) * NE + lane] = acc[i];
}

// ------------- softmax + top2 candidates + l_aux me partials ------------------
__global__ __launch_bounds__(256) void k_soft(const float* __restrict__ part,
                                              float2* __restrict__ g12,
                                              int* __restrict__ idxs,
                                              float* __restrict__ me_part) {
  __shared__ float lg[256][33];
  const int tid = threadIdx.x;
  const int R = blockIdx.x * 256 + tid;  // R = t*2 + p
  const int t = R >> 1;
  const int p = R & 1;
  float v[32];
  const float* pr = part + (size_t)t * NE + p * EE;
#pragma unroll
  for (int e = 0; e < 32; e += 4) {
    float4 s = *reinterpret_cast<const float4*>(pr + e);
    v[e] = s.x; v[e + 1] = s.y; v[e + 2] = s.z; v[e + 3] = s.w;
  }
  for (int kc = 1; kc < NKC; ++kc) {
    const float* prk = pr + (size_t)kc * T_TOK * NE;
#pragma unroll
    for (int e = 0; e < 32; e += 4) {
      float4 s = *reinterpret_cast<const float4*>(prk + e);
      v[e] += s.x; v[e + 1] += s.y; v[e + 2] += s.z; v[e + 3] += s.w;
    }
  }
  float m = v[0];
#pragma unroll
  for (int e = 1; e < 32; ++e) m = fmaxf(m, v[e]);
  float sum = 0.f;
#pragma unroll
  for (int e = 0; e < 32; ++e) { v[e] = expf(v[e] - m); sum += v[e]; }
  const float inv = 1.0f / sum;
#pragma unroll
  for (int e = 0; e < 32; ++e) v[e] *= inv;
  float g1 = -1.f; int i1 = 0;
#pragma unroll
  for (int e = 0; e < 32; ++e) if (v[e] > g1) { g1 = v[e]; i1 = e; }  // first-max, like jnp.argmax
  float g2 = -1.f; int i2 = 0;
#pragma unroll
  for (int e = 0; e < 32; ++e) if (e != i1 && v[e] > g2) { g2 = v[e]; i2 = e; }
  g12[R] = make_float2(g1, g2);
  idxs[R] = i1 | (i2 << 8);
#pragma unroll
  for (int e = 0; e < 32; ++e) lg[tid][e] = v[e];
  __syncthreads();
  if (tid < 64) {  // deterministic me partial per (p, e)
    const int p2 = tid >> 5, el = tid & 31;
    float s = 0.f;
    for (int rr = p2; rr < 256; rr += 2) s += lg[rr][el];
    me_part[blockIdx.x * 64 + tid] = s;
  }
}

// ------- ordered scans: queue positions, capacity, l_aux, final weights -------
__global__ __launch_bounds__(1024) void k_scan(const int* __restrict__ idxs,
                                               const float2* __restrict__ g12,
                                               const float* __restrict__ me_part,
                                               int2* __restrict__ fl,
                                               float2* __restrict__ wv,
                                               float* __restrict__ out) {
  __shared__ unsigned short loc1[NP][T_TOK];
  __shared__ int cnt[NP][8][32];
  __shared__ int pre[NP][8][32];
  __shared__ int base[NP][32];
  __shared__ float red[64];
  const int tid = threadIdx.x;
  const int p = tid >> 9;          // waves 0-7 -> p=0, 8-15 -> p=1
  const int w = (tid >> 6) & 7;
  const int l = tid & 63;
  if (tid < 64) base[tid >> 5][tid & 31] = 0;
  __syncthreads();
  // ---- scan 1: first-choice queue positions (pre-capacity cumsum) ----
  for (int pass = 0; pass < 8; ++pass) {
    const int t = pass * 512 + w * 64 + l;
    const int e1 = idxs[t * 2 + p] & 255;
    unsigned long long meq = 0; int myc = 0;
    for (int eb = 0; eb < 32; ++eb) {
      unsigned long long bm = __ballot(e1 == eb);
      if (e1 == eb) meq = bm;
      if (l == eb) myc = __popcll(bm);
    }
    if (l < 32) cnt[p][w][l] = myc;
    __syncthreads();
    if (tid < 64) {
      const int pp = tid >> 5, eb = tid & 31;
      int s = base[pp][eb];
      for (int ww = 0; ww < 8; ++ww) { pre[pp][ww][eb] = s; s += cnt[pp][ww][eb]; }
      base[pp][eb] = s;
    }
    __syncthreads();
    const int rank = pre[p][w][e1] + (int)__popcll(meq & ((1ull << l) - 1ull));
    loc1[p][t] = (unsigned short)rank;
    __syncthreads();
  }
  // ---- l_aux (uses pre-drop counts) + init scan2 base = kept1 counts ----
  if (tid < 64) {
    const int pp = tid >> 5, eb = tid & 31;
    float s = 0.f;
    for (int b = 0; b < 32; ++b) s += me_part[b * 64 + tid];
    red[tid] = s * (float)base[pp][eb];
    base[pp][eb] = min(base[pp][eb], CAP);  // second queue starts after kept first-choosers
  }
  __syncthreads();
  if (tid == 0) {
    float s = 0.f;
    for (int i = 0; i < 64; ++i) s += red[i];
    out[0] = s / (64.0f * 4096.0f * 4096.0f);
  }
  // ---- scan 2 (dropped tokens re-pick their top-1, per reference) + finalize ----
  for (int pass = 0; pass < 8; ++pass) {
    const int t = pass * 512 + w * 64 + l;
    const int R = t * 2 + p;
    const int ii = idxs[R];
    const int el1 = ii & 255;
    const int el2c = ii >> 8;
    const int lc1 = loc1[p][t];
    const bool kept1 = lc1 < CAP;
    const int e2 = kept1 ? el2c : el1;
    unsigned long long meq = 0; int myc = 0;
    for (int eb = 0; eb < 32; ++eb) {
      unsigned long long bm = __ballot(e2 == eb);
      if (e2 == eb) meq = bm;
      if (l == eb) myc = __popcll(bm);
    }
    if (l < 32) cnt[p][w][l] = myc;
    __syncthreads();
    if (tid < 64) {
      const int pp = tid >> 5, eb = tid & 31;
      int s = base[pp][eb];
      for (int ww = 0; ww < 8; ++ww) { pre[pp][ww][eb] = s; s += cnt[pp][ww][eb]; }
      base[pp][eb] = s;
    }
    __syncthreads();
    const int loc2 = pre[p][w][e2] + (int)__popcll(meq & ((1ull << l) - 1ull));
    const bool kept2 = loc2 < CAP;
    const float2 g = g12[R];
    const float gg2 = kept1 ? g.y : g.x;
    const float gs1 = kept1 ? g.x : 0.f;
    const float gs2 = kept2 ? gg2 : 0.f;
    const float den = fmaxf(gs1 + gs2, 1.1920929e-07f);  // FLT_EPSILON
    fl[R] = make_int2(kept1 ? el1 * CAP + lc1 : -1, kept2 ? e2 * CAP + loc2 : -1);
    wv[R] = make_float2(gs1 / den, gs2 / den);
    __syncthreads();
  }
}

// --------------------------- dense output writer -----------------------------
__global__ __launch_bounds__(256) void k_write(const int2* __restrict__ fl,
                                               const float2* __restrict__ wv,
                                               float* __restrict__ out,
                                               int dlimit) {
  const int R = blockIdx.x;
  const int tid = threadIdx.x;
  const int2 f = fl[R];
  const float2 ww = wv[R];
  float* oc = out + 1 + (size_t)R * 5120;
  float* od = out + 1 + COMB_ELEMS + (size_t)R * 5120;
  const bool dod = R < dlimit;
#pragma unroll
  for (int j = 0; j < 20; ++j) {
    const int i = tid + j * 256;
    const float val = (i == f.x) ? ww.x : ((i == f.y) ? ww.y : 0.f);
    oc[i] = val;
    if (dod) od[i] = (val != 0.f) ? 1.f : 0.f;
  }
}

__global__ __launch_bounds__(1024) void k_write_tail(const int2* __restrict__ fl,
                                                     const float2* __restrict__ wv,
                                                     float* __restrict__ out,
                                                     int rstart) {
  __shared__ int2 sfl[16];
  __shared__ float2 swv[16];
  const int tid = threadIdx.x;
  const int nr = 8192 - rstart;
  if (tid < nr) { sfl[tid] = fl[rstart + tid]; swv[tid] = wv[rstart + tid]; }
  __syncthreads();
  for (int j = tid; j < nr * 5120; j += 1024) {
    const int rr = j / 5120;
    const int i = j - rr * 5120;
    const float val = (i == sfl[rr].x) ? swv[rr].x : ((i == sfl[rr].y) ? swv[rr].y : 0.f);
    out[1 + COMB_ELEMS + (size_t)(rstart + rr) * 5120 + i] = (val != 0.f) ? 1.f : 0.f;
  }
}

extern "C" void kernel_launch(void* const* d_in, const int* in_sizes, int n_in,
                              void* d_out, int out_size, void* d_ws, size_t ws_size,
                              hipStream_t stream) {
  const float* x = (const float*)d_in[0];
  const float* W = (const float*)d_in[1];
  float* out = (float*)d_out;

  const size_t SMALLF = 59392;                       // floats of small scratch
  const size_t PARTF = (size_t)NKC * T_TOK * NE;     // 2,097,152 floats

  float* small;
  float* part;
  bool split = false;
  if (ws_size >= (SMALLF + PARTF) * sizeof(float)) {
    small = (float*)d_ws;
    part = small + SMALLF;
  } else if (ws_size >= SMALLF * sizeof(float)) {
    small = (float*)d_ws;
    part = out + 4;  // front of combine region, dead before writer runs
  } else {
    // everything inside d_out; small scratch at aligned tail, writer split to
    // avoid cross-block read/overwrite races (tail rewritten only by the
    // single-block tail writer after it has staged scratch into LDS).
    const size_t tb = (OUT_ELEMS - SMALLF) & ~(size_t)3;
    small = out + tb;
    part = out + 4;
    split = true;
  }
  float2* g12 = (float2*)small;
  int* idxs = (int*)(small + 16384);
  float* me_part = small + 24576;
  int2* fl = (int2*)(small + 26624);
  float2* wvp = (float2*)(small + 43008);

  hipLaunchKernelGGL(k_gemm, dim3(1024), dim3(256), 0, stream, x, W, part);
  hipLaunchKernelGGL(k_soft, dim3(32), dim3(256), 0, stream, part, g12, idxs, me_part);
  hipLaunchKernelGGL(k_scan, dim3(1), dim3(1024), 0, stream, idxs, g12, me_part, fl, wvp, out);
  if (!split) {
    hipLaunchKernelGGL(k_write, dim3(8192), dim3(256), 0, stream, fl, wvp, out, 8192);
  } else {
    const size_t tb = (OUT_ELEMS - SMALLF) & ~(size_t)3;
    const int rsplit = (int)((tb - (1 + COMB_ELEMS)) / 5120);  // = 8180
    hipLaunchKernelGGL(k_write, dim3(8192), dim3(256), 0, stream, fl, wvp, out, rsplit);
    hipLaunchKernelGGL(k_write_tail, dim3(1), dim3(1024), 0, stream, fl, wvp, out, rsplit);
  }
}

// Round 4
// 179.011 us; speedup vs baseline: 1.0457x; 1.0457x over previous
//
#include <hip/hip_runtime.h>
#include <cstdint>

#define T_TOK 4096
#define KDIM 2048
#define NE 64
#define NP 2
#define EE 32
#define CAP 160
#define NKC 8
#define KCHUNK 256
#define KSUB 128
#define COMB_ELEMS 41943040ull /* 8192 * 5120 */
#define OUT_ELEMS 83886081ull  /* 1 + 2*COMB */
#define SMALLF 65536           /* floats of small scratch */

// ---------------- GEMM: logits partials, K split into 8 chunks ----------------
__global__ __launch_bounds__(256) void k_gemm(const float* __restrict__ x,
                                              const float* __restrict__ W,
                                              float* __restrict__ part) {
  __shared__ float wt[KSUB][NE + 1];  // [k][e], pad -> conflict-free
  const int tid = threadIdx.x;
  const int rb = blockIdx.x & 127;   // 128 row-blocks of 32 rows
  const int kc = blockIdx.x >> 7;    // 8 k-chunks of 256
  const int lane = tid & 63;         // lane = global expert e
  const int rg = __builtin_amdgcn_readfirstlane(tid >> 6);
  const int r0 = rb * 32 + rg * 8;
  float acc[8];
#pragma unroll
  for (int i = 0; i < 8; ++i) acc[i] = 0.f;

  for (int sub = 0; sub < 2; ++sub) {
    const int kbase = kc * KCHUNK + sub * KSUB;
    __syncthreads();
#pragma unroll
    for (int it = 0; it < 32; ++it) {  // 64e x 128k cooperative load, transposed
      int idx = tid + it * 256;
      int e = idx >> 7;
      int k = idx & 127;
      wt[k][e] = W[e * KDIM + kbase + k];
    }
    __syncthreads();
    for (int k = 0; k < KSUB; k += 4) {
      float w0 = wt[k][lane], w1 = wt[k + 1][lane];
      float w2 = wt[k + 2][lane], w3 = wt[k + 3][lane];
#pragma unroll
      for (int i = 0; i < 8; ++i) {
        // wave-uniform address -> s_load_dwordx4
        const float4 xv = *reinterpret_cast<const float4*>(
            &x[(size_t)(r0 + i) * KDIM + kbase + k]);
        acc[i] = fmaf(xv.w, w3, fmaf(xv.z, w2, fmaf(xv.y, w1, fmaf(xv.x, w0, acc[i]))));
      }
    }
  }
#pragma unroll
  for (int i = 0; i < 8; ++i)
    part[((size_t)kc * T_TOK + (r0 + i)) * NE + lane] = acc[i];
}

// ------------- softmax + top2 candidates + l_aux me partials ------------------
__global__ __launch_bounds__(64) void k_soft(const float* __restrict__ part,
                                             float2* __restrict__ g12,
                                             int* __restrict__ idxs,
                                             float* __restrict__ me_part) {
  __shared__ float lg[64][33];
  const int tid = threadIdx.x;
  const int R = blockIdx.x * 64 + tid;  // R = t*2 + p
  const int t = R >> 1;
  const int p = R & 1;
  float v[32];
  const float* pr = part + (size_t)t * NE + p * EE;
#pragma unroll
  for (int e = 0; e < 32; e += 4) {
    float4 s = *reinterpret_cast<const float4*>(pr + e);
    v[e] = s.x; v[e + 1] = s.y; v[e + 2] = s.z; v[e + 3] = s.w;
  }
  for (int kc = 1; kc < NKC; ++kc) {
    const float* prk = pr + (size_t)kc * T_TOK * NE;
#pragma unroll
    for (int e = 0; e < 32; e += 4) {
      float4 s = *reinterpret_cast<const float4*>(prk + e);
      v[e] += s.x; v[e + 1] += s.y; v[e + 2] += s.z; v[e + 3] += s.w;
    }
  }
  float m = v[0];
#pragma unroll
  for (int e = 1; e < 32; ++e) m = fmaxf(m, v[e]);
  float sum = 0.f;
#pragma unroll
  for (int e = 0; e < 32; ++e) { v[e] = expf(v[e] - m); sum += v[e]; }
  const float inv = 1.0f / sum;
#pragma unroll
  for (int e = 0; e < 32; ++e) v[e] *= inv;
  float g1 = -1.f; int i1 = 0;
#pragma unroll
  for (int e = 0; e < 32; ++e) if (v[e] > g1) { g1 = v[e]; i1 = e; }  // first-max, like jnp.argmax
  float g2 = -1.f; int i2 = 0;
#pragma unroll
  for (int e = 0; e < 32; ++e) if (e != i1 && v[e] > g2) { g2 = v[e]; i2 = e; }
  g12[R] = make_float2(g1, g2);
  idxs[R] = i1 | (i2 << 8);
#pragma unroll
  for (int e = 0; e < 32; ++e) lg[tid][e] = v[e];
  __syncthreads();
  {  // deterministic me partial per (p, e): p = row parity within this block
    const int pp = tid >> 5, ee = tid & 31;
    float s = 0.f;
    for (int rr = pp; rr < 64; rr += 2) s += lg[rr][ee];
    me_part[blockIdx.x * 64 + tid] = s;
  }
}

// ------- hierarchical ordered scans: 5 barriers total (was 48) ---------------
__global__ __launch_bounds__(1024) void k_scan(const int* __restrict__ idxs,
                                               const float2* __restrict__ g12,
                                               const float* __restrict__ me_part,
                                               int2* __restrict__ fl,
                                               float2* __restrict__ wvp,
                                               float* __restrict__ out) {
  __shared__ int grp[NP][64][32];          // per-group counts -> exclusive prefixes
  __shared__ int tot[NP][32];
  __shared__ unsigned short tk1[NP][T_TOK];  // rank|e<<6, then loc1
  __shared__ unsigned short tk2[NP][T_TOK];  // rank2|e2<<6
  __shared__ float red[64];
  const int tid = threadIdx.x;
  const int wvi = tid >> 6;
  const int p = wvi >> 3;
  const int wg = wvi & 7;            // 8 waves per p, 8 groups of 64 tokens each
  const int l = tid & 63;
  const unsigned long long lmask = (1ull << l) - 1ull;
  // ---- Phase A1: per-group ballot counts + in-group rank (no barriers) ----
  for (int gi = 0; gi < 8; ++gi) {
    const int g = wg * 8 + gi;
    const int t = g * 64 + l;
    const int e1 = idxs[t * 2 + p] & 255;
    unsigned long long meq = 0; int myc = 0;
    for (int eb = 0; eb < 32; ++eb) {
      unsigned long long bm = __ballot(e1 == eb);
      if (e1 == eb) meq = bm;
      if (l == eb) myc = __popcll(bm);
    }
    if (l < 32) grp[p][g][l] = myc;
    tk1[p][t] = (unsigned short)((int)__popcll(meq & lmask) | (e1 << 6));
  }
  __syncthreads();
  // ---- Phase B1: exclusive prefix over 64 groups per (p,e) ----
  if (tid < 64) {
    const int pp = tid >> 5, ee = tid & 31;
    int s = 0;
    for (int g = 0; g < 64; ++g) { int vv = grp[pp][g][ee]; grp[pp][g][ee] = s; s += vv; }
    tot[pp][ee] = s;
  }
  __syncthreads();
  // ---- Phase C1: loc1 per token; l_aux partial per (p,e) ----
  for (int gi = 0; gi < 8; ++gi) {
    const int g = wg * 8 + gi;
    const int t = g * 64 + l;
    const int vv = tk1[p][t];
    tk1[p][t] = (unsigned short)(grp[p][g][vv >> 6] + (vv & 63));
  }
  if (tid < 64) {
    float s = 0.f;
    for (int b = 0; b < 128; ++b) s += me_part[b * 64 + tid];
    red[tid] = s * (float)tot[tid >> 5][tid & 31];   // pre-drop counts
  }
  __syncthreads();  // also protects grp reuse by A2
  if (tid == 0) {
    float s = 0.f;
    for (int i = 0; i < 64; ++i) s += red[i];
    out[0] = s / (64.0f * 4096.0f * 4096.0f);
  }
  // ---- Phase A2: dropped tokens re-pick their top-1 (reference semantics) ----
  for (int gi = 0; gi < 8; ++gi) {
    const int g = wg * 8 + gi;
    const int t = g * 64 + l;
    const int ii = idxs[t * 2 + p];
    const int e2 = (tk1[p][t] < CAP) ? (ii >> 8) : (ii & 255);
    unsigned long long meq = 0; int myc = 0;
    for (int eb = 0; eb < 32; ++eb) {
      unsigned long long bm = __ballot(e2 == eb);
      if (e2 == eb) meq = bm;
      if (l == eb) myc = __popcll(bm);
    }
    if (l < 32) grp[p][g][l] = myc;
    tk2[p][t] = (unsigned short)((int)__popcll(meq & lmask) | (e2 << 6));
  }
  __syncthreads();
  // ---- Phase B2: prefix starting at kept-first-chooser counts ----
  if (tid < 64) {
    const int pp = tid >> 5, ee = tid & 31;
    int s = min(tot[pp][ee], CAP);
    for (int g = 0; g < 64; ++g) { int vv = grp[pp][g][ee]; grp[pp][g][ee] = s; s += vv; }
  }
  __syncthreads();
  // ---- Phase C2: finalize positions + weights ----
  for (int gi = 0; gi < 8; ++gi) {
    const int g = wg * 8 + gi;
    const int t = g * 64 + l;
    const int R = t * 2 + p;
    const int ii = idxs[R];
    const int e1 = ii & 255;
    const int loc1v = tk1[p][t];
    const bool kept1 = loc1v < CAP;
    const int v2 = tk2[p][t];
    const int rank2 = v2 & 63, e2 = v2 >> 6;
    const int loc2 = grp[p][g][e2] + rank2;
    const bool kept2 = loc2 < CAP;
    const float2 gg = g12[R];
    const float gs1 = kept1 ? gg.x : 0.f;
    const float g2v = kept1 ? gg.y : gg.x;
    const float gs2 = kept2 ? g2v : 0.f;
    const float den = fmaxf(gs1 + gs2, 1.1920929e-07f);  // FLT_EPSILON
    fl[R] = make_int2(kept1 ? e1 * CAP + loc1v : -1, kept2 ? e2 * CAP + loc2 : -1);
    wvp[R] = make_float2(gs1 / den, gs2 / den);
  }
}

// ------------- writer: pure float4 zero-fill + <=8 point fixes ---------------
__global__ __launch_bounds__(256) void k_write(const int2* __restrict__ fl,
                                               const float2* __restrict__ wvp,
                                               float* __restrict__ out,
                                               int nfullB) {
  const int b = blockIdx.x;          // owns rows 2b, 2b+1 (two 5120-float rows)
  const int tid = threadIdx.x;
  int fpos = -1; float fval = 0.f; size_t faddr = 0;
  if (tid < 8) {
    const int region = tid >> 2;     // 0=combine, 1=dispatch
    const int rr = 2 * b + ((tid >> 1) & 1);
    const int2 f = fl[rr];
    const float2 w = wvp[rr];
    const int which = tid & 1;
    fpos = which ? f.y : f.x;
    fval = region ? 1.0f : (which ? w.y : w.x);
    faddr = 1ull + (region ? COMB_ELEMS : 0ull) + (size_t)rr * 5120 + (size_t)(fpos < 0 ? 0 : fpos);
    if (region && b >= nfullB) fpos = -1;   // deferred to tail kernel
  }
  const float4 z4 = make_float4(0.f, 0.f, 0.f, 0.f);
  const size_t cb = 1 + (size_t)b * 10240;  // span start (float index), == 1 mod 4
  {
    float4* p4 = (float4*)(out + cb + 3);   // 16B-aligned
#pragma unroll
    for (int j = 0; j < 10; ++j) {
      const int idx = tid + j * 256;
      if (idx < 2559) p4[idx] = z4;
    }
    if (tid < 3) out[cb + tid] = 0.f;
    if (tid == 3) out[cb + 10239] = 0.f;
  }
  if (b < nfullB) {
    float4* p4 = (float4*)(out + COMB_ELEMS + cb + 3);
#pragma unroll
    for (int j = 0; j < 10; ++j) {
      const int idx = tid + j * 256;
      if (idx < 2559) p4[idx] = z4;
    }
    if (tid < 3) out[COMB_ELEMS + cb + tid] = 0.f;
    if (tid == 3) out[COMB_ELEMS + cb + 10239] = 0.f;
  }
  __syncthreads();
  if (tid < 8 && fpos >= 0) out[faddr] = fval;
}

// tail writer for the all-in-d_out aliasing path: stages fl/wv in LDS first
__global__ __launch_bounds__(1024) void k_write_tail(const int2* __restrict__ fl,
                                                     const float2* __restrict__ wvp,
                                                     float* __restrict__ out,
                                                     int nfullB) {
  __shared__ int2 sfl[16];
  const int tid = threadIdx.x;
  const int rstart = nfullB * 2;
  const int nr = 8192 - rstart;      // <= 16
  if (tid < nr) sfl[tid] = fl[rstart + tid];
  __syncthreads();
  const size_t base = 1 + COMB_ELEMS + (size_t)rstart * 5120;  // == 1 mod 4
  const int cnt = nr * 5120;
  const int nx4 = (cnt - 4) >> 2;
  float4* p4 = (float4*)(out + base + 3);
  const float4 z4 = make_float4(0.f, 0.f, 0.f, 0.f);
  for (int idx = tid; idx < nx4; idx += 1024) p4[idx] = z4;
  if (tid < 3) out[base + tid] = 0.f;
  if (tid == 3) out[base + cnt - 1] = 0.f;
  __syncthreads();
  if (tid < 2 * nr) {
    const int rr = rstart + (tid >> 1);
    const int2 f = sfl[tid >> 1];
    const int pos = (tid & 1) ? f.y : f.x;
    if (pos >= 0) out[1 + COMB_ELEMS + (size_t)rr * 5120 + pos] = 1.0f;
  }
}

extern "C" void kernel_launch(void* const* d_in, const int* in_sizes, int n_in,
                              void* d_out, int out_size, void* d_ws, size_t ws_size,
                              hipStream_t stream) {
  const float* x = (const float*)d_in[0];
  const float* W = (const float*)d_in[1];
  float* out = (float*)d_out;

  const size_t PARTF = (size_t)NKC * T_TOK * NE;  // 2,097,152 floats

  float* small;
  float* part;
  int nfullB = 4096;
  if (ws_size >= (SMALLF + PARTF) * sizeof(float)) {
    small = (float*)d_ws;
    part = small + SMALLF;
  } else if (ws_size >= SMALLF * sizeof(float)) {
    small = (float*)d_ws;
    part = out + 4;  // front of combine region, dead before writer runs
  } else {
    // everything inside d_out; scratch at aligned tail; dispatch spans that
    // overlap the scratch are deferred to the single-block tail writer.
    const size_t tb = (OUT_ELEMS - SMALLF) & ~(size_t)3;  // 83820544
    small = out + tb;
    part = out + 4;
    nfullB = (int)((tb - 1 - COMB_ELEMS) / 10240);        // 4089
  }
  float2* g12 = (float2*)small;                 // 16384 floats
  int* idxs = (int*)(small + 16384);            //  8192
  float* me_part = small + 24576;               //  8192
  int2* fl = (int2*)(small + 32768);            // 16384
  float2* wvp = (float2*)(small + 49152);       // 16384  -> total 65536

  hipLaunchKernelGGL(k_gemm, dim3(1024), dim3(256), 0, stream, x, W, part);
  hipLaunchKernelGGL(k_soft, dim3(128), dim3(64), 0, stream, part, g12, idxs, me_part);
  hipLaunchKernelGGL(k_scan, dim3(1), dim3(1024), 0, stream, idxs, g12, me_part, fl, wvp, out);
  hipLaunchKernelGGL(k_write, dim3(4096), dim3(256), 0, stream, fl, wvp, out, nfullB);
  if (nfullB < 4096)
    hipLaunchKernelGGL(k_write_tail, dim3(1), dim3(1024), 0, stream, fl, wvp, out, nfullB);
}

// Round 5
// 143.029 us; speedup vs baseline: 1.3088x; 1.2516x over previous
//
#include <hip/hip_runtime.h>
#include <cstdint>

#define T_TOK 4096
#define KDIM 2048
#define NE 64
#define NP 2
#define EE 32
#define CAP 160
#define NKC 8
#define KCHUNK 256
#define COMB_ELEMS 41943040ull /* 8192 * 5120 */
#define OUT_ELEMS 83886081ull  /* 1 + 2*COMB */
#define SMALLF 65536           /* floats of small scratch */

// -------- GEMM v2: 64r x 64e tile, both operands LDS-staged, per-thread 4x4 --
__global__ __launch_bounds__(256) void k_gemm(const float* __restrict__ x,
                                              const float* __restrict__ W,
                                              float* __restrict__ part) {
  __shared__ float xs[64][33];  // 4-row stride 132 == 4 mod 32 -> conflict-free
  __shared__ float wt[32][65];  // [k][e], 16-lane b128 span = 2-way (free)
  const int tid = threadIdx.x;
  const int rb = blockIdx.x & 63;   // 64 row-blocks of 64 rows
  const int kc = blockIdx.x >> 6;   // 8 k-chunks of 256
  const int r0 = rb * 64;
  const int er = tid & 15;          // e0 = er*4
  const int rg = tid >> 4;          // local rows rg*4..+3
  float acc[4][4];
#pragma unroll
  for (int i = 0; i < 4; ++i)
#pragma unroll
    for (int j = 0; j < 4; ++j) acc[i][j] = 0.f;

  for (int s = 0; s < 8; ++s) {     // 8 sub-chunks of 32 k
    const int kbase = kc * KCHUNK + s * 32;
    __syncthreads();
#pragma unroll
    for (int q = 0; q < 2; ++q) {   // x tile: 64r x 32k, coalesced float4
      const int li = tid + q * 256;
      const int row = li >> 3, kq = (li & 7) * 4;
      const float4 v = *reinterpret_cast<const float4*>(
          &x[(size_t)(r0 + row) * KDIM + kbase + kq]);
      *reinterpret_cast<float4*>(&xs[row][kq]) = v;
    }
#pragma unroll
    for (int q = 0; q < 2; ++q) {   // w tile: 64e x 32k load, transposed store
      const int li = tid + q * 256;
      const int e = li >> 3, kq = (li & 7) * 4;
      const float4 v = *reinterpret_cast<const float4*>(
          &W[(size_t)e * KDIM + kbase + kq]);
      wt[kq][e] = v.x; wt[kq + 1][e] = v.y; wt[kq + 2][e] = v.z; wt[kq + 3][e] = v.w;
    }
    __syncthreads();
#pragma unroll
    for (int k4 = 0; k4 < 8; ++k4) {  // 8 x (4k): 8 b128 LDS reads, 64 FMA
      float4 xa[4], wb[4];
#pragma unroll
      for (int i = 0; i < 4; ++i)
        xa[i] = *reinterpret_cast<const float4*>(&xs[rg * 4 + i][k4 * 4]);
#pragma unroll
      for (int j = 0; j < 4; ++j)
        wb[j] = *reinterpret_cast<const float4*>(&wt[k4 * 4 + j][er * 4]);
#pragma unroll
      for (int i = 0; i < 4; ++i) {
        const float x0 = xa[i].x, x1 = xa[i].y, x2 = xa[i].z, x3 = xa[i].w;
        // k ascending (x0*w[k] .. x3*w[k+3]) keeps FP order == previous rounds
        acc[i][0] = fmaf(x3, wb[3].x, fmaf(x2, wb[2].x, fmaf(x1, wb[1].x, fmaf(x0, wb[0].x, acc[i][0]))));
        acc[i][1] = fmaf(x3, wb[3].y, fmaf(x2, wb[2].y, fmaf(x1, wb[1].y, fmaf(x0, wb[0].y, acc[i][1]))));
        acc[i][2] = fmaf(x3, wb[3].z, fmaf(x2, wb[2].z, fmaf(x1, wb[1].z, fmaf(x0, wb[0].z, acc[i][2]))));
        acc[i][3] = fmaf(x3, wb[3].w, fmaf(x2, wb[2].w, fmaf(x1, wb[1].w, fmaf(x0, wb[0].w, acc[i][3]))));
      }
    }
  }
#pragma unroll
  for (int i = 0; i < 4; ++i) {
    float4 v; v.x = acc[i][0]; v.y = acc[i][1]; v.z = acc[i][2]; v.w = acc[i][3];
    *reinterpret_cast<float4*>(
        &part[((size_t)kc * T_TOK + r0 + rg * 4 + i) * NE + er * 4]) = v;
  }
}

// ------------- softmax + top2 candidates + l_aux me partials ------------------
__global__ __launch_bounds__(64) void k_soft(const float* __restrict__ part,
                                             float2* __restrict__ g12,
                                             int* __restrict__ idxs,
                                             float* __restrict__ me_part) {
  __shared__ float lg[64][33];
  const int tid = threadIdx.x;
  const int R = blockIdx.x * 64 + tid;  // R = t*2 + p
  const int t = R >> 1;
  const int p = R & 1;
  float v[32];
  const float* pr = part + (size_t)t * NE + p * EE;
#pragma unroll
  for (int e = 0; e < 32; e += 4) {
    float4 s = *reinterpret_cast<const float4*>(pr + e);
    v[e] = s.x; v[e + 1] = s.y; v[e + 2] = s.z; v[e + 3] = s.w;
  }
  for (int kc = 1; kc < NKC; ++kc) {
    const float* prk = pr + (size_t)kc * T_TOK * NE;
#pragma unroll
    for (int e = 0; e < 32; e += 4) {
      float4 s = *reinterpret_cast<const float4*>(prk + e);
      v[e] += s.x; v[e + 1] += s.y; v[e + 2] += s.z; v[e + 3] += s.w;
    }
  }
  float m = v[0];
#pragma unroll
  for (int e = 1; e < 32; ++e) m = fmaxf(m, v[e]);
  float sum = 0.f;
#pragma unroll
  for (int e = 0; e < 32; ++e) { v[e] = expf(v[e] - m); sum += v[e]; }
  const float inv = 1.0f / sum;
#pragma unroll
  for (int e = 0; e < 32; ++e) v[e] *= inv;
  float g1 = -1.f; int i1 = 0;
#pragma unroll
  for (int e = 0; e < 32; ++e) if (v[e] > g1) { g1 = v[e]; i1 = e; }  // first-max, like jnp.argmax
  float g2 = -1.f; int i2 = 0;
#pragma unroll
  for (int e = 0; e < 32; ++e) if (e != i1 && v[e] > g2) { g2 = v[e]; i2 = e; }
  g12[R] = make_float2(g1, g2);
  idxs[R] = i1 | (i2 << 8);
#pragma unroll
  for (int e = 0; e < 32; ++e) lg[tid][e] = v[e];
  __syncthreads();
  {  // deterministic me partial per (p, e): p = row parity within this block
    const int pp = tid >> 5, ee = tid & 31;
    float s = 0.f;
    for (int rr = pp; rr < 64; rr += 2) s += lg[rr][ee];
    me_part[blockIdx.x * 64 + tid] = s;
  }
}

// ------- hierarchical ordered scans: 5 barriers total ------------------------
__global__ __launch_bounds__(1024) void k_scan(const int* __restrict__ idxs,
                                               const float2* __restrict__ g12,
                                               const float* __restrict__ me_part,
                                               int2* __restrict__ fl,
                                               float2* __restrict__ wvp,
                                               float* __restrict__ out) {
  __shared__ int grp[NP][64][32];          // per-group counts -> exclusive prefixes
  __shared__ int tot[NP][32];
  __shared__ unsigned short tk1[NP][T_TOK];  // rank|e<<6, then loc1
  __shared__ unsigned short tk2[NP][T_TOK];  // rank2|e2<<6
  __shared__ float red[64];
  const int tid = threadIdx.x;
  const int wvi = tid >> 6;
  const int p = wvi >> 3;
  const int wg = wvi & 7;            // 8 waves per p, 8 groups of 64 tokens each
  const int l = tid & 63;
  const unsigned long long lmask = (1ull << l) - 1ull;
  // ---- Phase A1: per-group ballot counts + in-group rank (no barriers) ----
  for (int gi = 0; gi < 8; ++gi) {
    const int g = wg * 8 + gi;
    const int t = g * 64 + l;
    const int e1 = idxs[t * 2 + p] & 255;
    unsigned long long meq = 0; int myc = 0;
    for (int eb = 0; eb < 32; ++eb) {
      unsigned long long bm = __ballot(e1 == eb);
      if (e1 == eb) meq = bm;
      if (l == eb) myc = __popcll(bm);
    }
    if (l < 32) grp[p][g][l] = myc;
    tk1[p][t] = (unsigned short)((int)__popcll(meq & lmask) | (e1 << 6));
  }
  __syncthreads();
  // ---- Phase B1: exclusive prefix over 64 groups per (p,e) ----
  if (tid < 64) {
    const int pp = tid >> 5, ee = tid & 31;
    int s = 0;
    for (int g = 0; g < 64; ++g) { int vv = grp[pp][g][ee]; grp[pp][g][ee] = s; s += vv; }
    tot[pp][ee] = s;
  }
  __syncthreads();
  // ---- Phase C1: loc1 per token; l_aux partial per (p,e) ----
  for (int gi = 0; gi < 8; ++gi) {
    const int g = wg * 8 + gi;
    const int t = g * 64 + l;
    const int vv = tk1[p][t];
    tk1[p][t] = (unsigned short)(grp[p][g][vv >> 6] + (vv & 63));
  }
  if (tid < 64) {
    float s = 0.f;
    for (int b = 0; b < 128; ++b) s += me_part[b * 64 + tid];
    red[tid] = s * (float)tot[tid >> 5][tid & 31];   // pre-drop counts
  }
  __syncthreads();  // also protects grp reuse by A2
  if (tid == 0) {
    float s = 0.f;
    for (int i = 0; i < 64; ++i) s += red[i];
    out[0] = s / (64.0f * 4096.0f * 4096.0f);
  }
  // ---- Phase A2: dropped tokens re-pick their top-1 (reference semantics) ----
  for (int gi = 0; gi < 8; ++gi) {
    const int g = wg * 8 + gi;
    const int t = g * 64 + l;
    const int ii = idxs[t * 2 + p];
    const int e2 = (tk1[p][t] < CAP) ? (ii >> 8) : (ii & 255);
    unsigned long long meq = 0; int myc = 0;
    for (int eb = 0; eb < 32; ++eb) {
      unsigned long long bm = __ballot(e2 == eb);
      if (e2 == eb) meq = bm;
      if (l == eb) myc = __popcll(bm);
    }
    if (l < 32) grp[p][g][l] = myc;
    tk2[p][t] = (unsigned short)((int)__popcll(meq & lmask) | (e2 << 6));
  }
  __syncthreads();
  // ---- Phase B2: prefix starting at kept-first-chooser counts ----
  if (tid < 64) {
    const int pp = tid >> 5, ee = tid & 31;
    int s = min(tot[pp][ee], CAP);
    for (int g = 0; g < 64; ++g) { int vv = grp[pp][g][ee]; grp[pp][g][ee] = s; s += vv; }
  }
  __syncthreads();
  // ---- Phase C2: finalize positions + weights ----
  for (int gi = 0; gi < 8; ++gi) {
    const int g = wg * 8 + gi;
    const int t = g * 64 + l;
    const int R = t * 2 + p;
    const int ii = idxs[R];
    const int e1 = ii & 255;
    const int loc1v = tk1[p][t];
    const bool kept1 = loc1v < CAP;
    const int v2 = tk2[p][t];
    const int rank2 = v2 & 63, e2 = v2 >> 6;
    const int loc2 = grp[p][g][e2] + rank2;
    const bool kept2 = loc2 < CAP;
    const float2 gg = g12[R];
    const float gs1 = kept1 ? gg.x : 0.f;
    const float g2v = kept1 ? gg.y : gg.x;
    const float gs2 = kept2 ? g2v : 0.f;
    const float den = fmaxf(gs1 + gs2, 1.1920929e-07f);  // FLT_EPSILON
    fl[R] = make_int2(kept1 ? e1 * CAP + loc1v : -1, kept2 ? e2 * CAP + loc2 : -1);
    wvp[R] = make_float2(gs1 / den, gs2 / den);
  }
}

// ---- writer: ONE contiguous 40KB stream per block (fill-equivalent) ---------
__global__ __launch_bounds__(256) void k_write(const int2* __restrict__ fl,
                                               const float2* __restrict__ wvp,
                                               float* __restrict__ out,
                                               int nfullB) {
  const int b = blockIdx.x;           // 0..4095 combine, 4096..8191 dispatch
  const int tid = threadIdx.x;
  const int region = b >> 12;
  const int bd = b & 4095;            // owns rows 2bd, 2bd+1
  if (region && bd >= nfullB) return; // deferred to tail kernel (scratch overlap)
  int fpos = -1; float fval = 0.f; size_t faddr = 0;
  if (tid < 4) {
    const int rr = 2 * bd + (tid >> 1);
    const int2 f = fl[rr];
    const float2 w = wvp[rr];
    const int which = tid & 1;
    fpos = which ? f.y : f.x;
    fval = region ? 1.0f : (which ? w.y : w.x);
    faddr = 1ull + (region ? COMB_ELEMS : 0ull) + (size_t)rr * 5120 + (size_t)(fpos < 0 ? 0 : fpos);
  }
  const size_t base = 1 + (region ? COMB_ELEMS : 0ull) + (size_t)bd * 10240;  // == 1 mod 4
  float4* p4 = (float4*)(out + base + 3);  // 16B-aligned
  const float4 z4 = make_float4(0.f, 0.f, 0.f, 0.f);
#pragma unroll
  for (int j = 0; j < 10; ++j) {
    const int idx = tid + j * 256;
    if (idx < 2559) p4[idx] = z4;
  }
  if (tid < 3) out[base + tid] = 0.f;
  if (tid == 3) out[base + 10239] = 0.f;
  __syncthreads();
  if (tid < 4 && fpos >= 0) out[faddr] = fval;
}

// tail writer for the all-in-d_out aliasing path: stages fl in LDS first
__global__ __launch_bounds__(1024) void k_write_tail(const int2* __restrict__ fl,
                                                     float* __restrict__ out,
                                                     int nfullB) {
  __shared__ int2 sfl[16];
  const int tid = threadIdx.x;
  const int rstart = nfullB * 2;
  const int nr = 8192 - rstart;      // <= 16
  if (tid < nr) sfl[tid] = fl[rstart + tid];
  __syncthreads();
  const size_t base = 1 + COMB_ELEMS + (size_t)rstart * 5120;  // == 1 mod 4
  const int cnt = nr * 5120;
  const int nx4 = (cnt - 4) >> 2;
  float4* p4 = (float4*)(out + base + 3);
  const float4 z4 = make_float4(0.f, 0.f, 0.f, 0.f);
  for (int idx = tid; idx < nx4; idx += 1024) p4[idx] = z4;
  if (tid < 3) out[base + tid] = 0.f;
  if (tid == 3) out[base + cnt - 1] = 0.f;
  __syncthreads();
  if (tid < 2 * nr) {
    const int rr = rstart + (tid >> 1);
    const int2 f = sfl[tid >> 1];
    const int pos = (tid & 1) ? f.y : f.x;
    if (pos >= 0) out[1 + COMB_ELEMS + (size_t)rr * 5120 + pos] = 1.0f;
  }
}

extern "C" void kernel_launch(void* const* d_in, const int* in_sizes, int n_in,
                              void* d_out, int out_size, void* d_ws, size_t ws_size,
                              hipStream_t stream) {
  const float* x = (const float*)d_in[0];
  const float* W = (const float*)d_in[1];
  float* out = (float*)d_out;

  const size_t PARTF = (size_t)NKC * T_TOK * NE;  // 2,097,152 floats

  float* small;
  float* part;
  int nfullB = 4096;
  if (ws_size >= (SMALLF + PARTF) * sizeof(float)) {
    small = (float*)d_ws;
    part = small + SMALLF;
  } else if (ws_size >= SMALLF * sizeof(float)) {
    small = (float*)d_ws;
    part = out + 4;  // front of combine region, dead before writer runs
  } else {
    // everything inside d_out; scratch at aligned tail; dispatch spans that
    // overlap the scratch are deferred to the single-block tail writer.
    const size_t tb = (OUT_ELEMS - SMALLF) & ~(size_t)3;  // 83820544
    small = out + tb;
    part = out + 4;
    nfullB = (int)((tb - 1 - COMB_ELEMS) / 10240);        // 4089
  }
  float2* g12 = (float2*)small;                 // 16384 floats
  int* idxs = (int*)(small + 16384);            //  8192
  float* me_part = small + 24576;               //  8192
  int2* fl = (int2*)(small + 32768);            // 16384
  float2* wvp = (float2*)(small + 49152);       // 16384  -> total 65536

  hipLaunchKernelGGL(k_gemm, dim3(512), dim3(256), 0, stream, x, W, part);
  hipLaunchKernelGGL(k_soft, dim3(128), dim3(64), 0, stream, part, g12, idxs, me_part);
  hipLaunchKernelGGL(k_scan, dim3(1), dim3(1024), 0, stream, idxs, g12, me_part, fl, wvp, out);
  hipLaunchKernelGGL(k_write, dim3(8192), dim3(256), 0, stream, fl, wvp, out, nfullB);
  if (nfullB < 4096)
    hipLaunchKernelGGL(k_write_tail, dim3(1), dim3(1024), 0, stream, fl, out, nfullB);
}

// Round 6
// 123.338 us; speedup vs baseline: 1.5177x; 1.1597x over previous
//
#include <hip/hip_runtime.h>
#include <cstdint>

#define T_TOK 4096
#define KDIM 2048
#define NE 64
#define NP 2
#define EE 32
#define CAP 160
#define NKC 8
#define KCHUNK 256
#define BLKR 128
#define COMB_ELEMS 41943040ull /* 8192 * 5120 */
#define OUT_ELEMS 83886081ull  /* 1 + 2*COMB */
#define SMALLF 65536           /* floats of small scratch */

// ---- GEMM v3: 128r x 64e x 256k per block, 8r x 4e per thread, b128 LDS ----
__global__ __launch_bounds__(256) void k_gemm(const float* __restrict__ x,
                                              const float* __restrict__ W,
                                              float* __restrict__ part) {
  __shared__ float xs[BLKR][36];  // stride 36: 16B-aligned, bank 9r+k (staggered)
  __shared__ float wt[32][68];    // [k][e] stride 68: 16B-aligned, staggered
  const int tid = threadIdx.x;
  const int rb = blockIdx.x & 31;  // 32 row-blocks of 128 rows
  const int kc = blockIdx.x >> 5;  // 8 k-chunks of 256
  const int r0 = rb * BLKR;
  const int er = tid & 15;         // experts er*4 .. +3
  const int rg = tid >> 4;         // rows rg + 16*i, i=0..7
  float acc[8][4];
#pragma unroll
  for (int i = 0; i < 8; ++i)
#pragma unroll
    for (int c = 0; c < 4; ++c) acc[i][c] = 0.f;

  float4 sx[4], sw[2];
  {  // issue sub-chunk 0
    const int kb = kc * KCHUNK;
#pragma unroll
    for (int q = 0; q < 4; ++q) {
      const int li = tid + q * 256, row = li >> 3, kq = (li & 7) * 4;
      sx[q] = *reinterpret_cast<const float4*>(&x[(size_t)(r0 + row) * KDIM + kb + kq]);
    }
#pragma unroll
    for (int q = 0; q < 2; ++q) {
      const int li = tid + q * 256, e = li >> 3, kq = (li & 7) * 4;
      sw[q] = *reinterpret_cast<const float4*>(&W[(size_t)e * KDIM + kb + kq]);
    }
  }
  for (int s = 0; s < 8; ++s) {    // 8 sub-chunks of 32 k
    __syncthreads();               // prev compute done reading LDS
#pragma unroll
    for (int q = 0; q < 4; ++q) {  // regs -> LDS
      const int li = tid + q * 256, row = li >> 3, kq = (li & 7) * 4;
      *reinterpret_cast<float4*>(&xs[row][kq]) = sx[q];
    }
#pragma unroll
    for (int q = 0; q < 2; ++q) {
      const int li = tid + q * 256, e = li >> 3, kq = (li & 7) * 4;
      wt[kq][e] = sw[q].x; wt[kq + 1][e] = sw[q].y;
      wt[kq + 2][e] = sw[q].z; wt[kq + 3][e] = sw[q].w;
    }
    if (s < 7) {                   // issue s+1: latency hides under compute(s)
      const int kb = kc * KCHUNK + (s + 1) * 32;
#pragma unroll
      for (int q = 0; q < 4; ++q) {
        const int li = tid + q * 256, row = li >> 3, kq = (li & 7) * 4;
        sx[q] = *reinterpret_cast<const float4*>(&x[(size_t)(r0 + row) * KDIM + kb + kq]);
      }
#pragma unroll
      for (int q = 0; q < 2; ++q) {
        const int li = tid + q * 256, e = li >> 3, kq = (li & 7) * 4;
        sw[q] = *reinterpret_cast<const float4*>(&W[(size_t)e * KDIM + kb + kq]);
      }
    }
    __syncthreads();               // LDS ready
#pragma unroll
    for (int k4 = 0; k4 < 8; ++k4) {
      float4 wb[4];
#pragma unroll
      for (int j = 0; j < 4; ++j)
        wb[j] = *reinterpret_cast<const float4*>(&wt[k4 * 4 + j][er * 4]);
#pragma unroll
      for (int i = 0; i < 8; ++i) {
        const float4 xv = *reinterpret_cast<const float4*>(&xs[rg + 16 * i][k4 * 4]);
        // k ascending nested fmaf: bitwise-identical accumulation order to R5
        acc[i][0] = fmaf(xv.w, wb[3].x, fmaf(xv.z, wb[2].x, fmaf(xv.y, wb[1].x, fmaf(xv.x, wb[0].x, acc[i][0]))));
        acc[i][1] = fmaf(xv.w, wb[3].y, fmaf(xv.z, wb[2].y, fmaf(xv.y, wb[1].y, fmaf(xv.x, wb[0].y, acc[i][1]))));
        acc[i][2] = fmaf(xv.w, wb[3].z, fmaf(xv.z, wb[2].z, fmaf(xv.y, wb[1].z, fmaf(xv.x, wb[0].z, acc[i][2]))));
        acc[i][3] = fmaf(xv.w, wb[3].w, fmaf(xv.z, wb[2].w, fmaf(xv.y, wb[1].w, fmaf(xv.x, wb[0].w, acc[i][3]))));
      }
    }
  }
#pragma unroll
  for (int i = 0; i < 8; ++i) {
    float4 v; v.x = acc[i][0]; v.y = acc[i][1]; v.z = acc[i][2]; v.w = acc[i][3];
    *reinterpret_cast<float4*>(
        &part[((size_t)kc * T_TOK + r0 + rg + 16 * i) * NE + er * 4]) = v;
  }
}

// ------------- softmax + top2 candidates + l_aux me partials ------------------
__global__ __launch_bounds__(64) void k_soft(const float* __restrict__ part,
                                             float2* __restrict__ g12,
                                             int* __restrict__ idxs,
                                             float* __restrict__ me_part) {
  __shared__ float lg[64][33];
  const int tid = threadIdx.x;
  const int R = blockIdx.x * 64 + tid;  // R = t*2 + p
  const int t = R >> 1;
  const int p = R & 1;
  float v[32];
  const float* pr = part + (size_t)t * NE + p * EE;
#pragma unroll
  for (int e = 0; e < 32; e += 4) {
    float4 s = *reinterpret_cast<const float4*>(pr + e);
    v[e] = s.x; v[e + 1] = s.y; v[e + 2] = s.z; v[e + 3] = s.w;
  }
  for (int kc = 1; kc < NKC; ++kc) {
    const float* prk = pr + (size_t)kc * T_TOK * NE;
#pragma unroll
    for (int e = 0; e < 32; e += 4) {
      float4 s = *reinterpret_cast<const float4*>(prk + e);
      v[e] += s.x; v[e + 1] += s.y; v[e + 2] += s.z; v[e + 3] += s.w;
    }
  }
  float m = v[0];
#pragma unroll
  for (int e = 1; e < 32; ++e) m = fmaxf(m, v[e]);
  float sum = 0.f;
#pragma unroll
  for (int e = 0; e < 32; ++e) { v[e] = expf(v[e] - m); sum += v[e]; }
  const float inv = 1.0f / sum;
#pragma unroll
  for (int e = 0; e < 32; ++e) v[e] *= inv;
  float g1 = -1.f; int i1 = 0;
#pragma unroll
  for (int e = 0; e < 32; ++e) if (v[e] > g1) { g1 = v[e]; i1 = e; }  // first-max, like jnp.argmax
  float g2 = -1.f; int i2 = 0;
#pragma unroll
  for (int e = 0; e < 32; ++e) if (e != i1 && v[e] > g2) { g2 = v[e]; i2 = e; }
  g12[R] = make_float2(g1, g2);
  idxs[R] = i1 | (i2 << 8);
#pragma unroll
  for (int e = 0; e < 32; ++e) lg[tid][e] = v[e];
  __syncthreads();
  {  // deterministic me partial per (p, e): p = row parity within this block
    const int pp = tid >> 5, ee = tid & 31;
    float s = 0.f;
    for (int rr = pp; rr < 64; rr += 2) s += lg[rr][ee];
    me_part[blockIdx.x * 64 + tid] = s;
  }
}

// ------- hierarchical ordered scans, 5-bit match trick -----------------------
__global__ __launch_bounds__(1024) void k_scan(const int* __restrict__ idxs,
                                               const float2* __restrict__ g12,
                                               const float* __restrict__ me_part,
                                               int2* __restrict__ fl,
                                               float2* __restrict__ wvp,
                                               float* __restrict__ out) {
  __shared__ int grp[NP][64][32];          // per-group counts -> exclusive prefixes
  __shared__ int tot[NP][32];
  __shared__ unsigned short tk1[NP][T_TOK];  // rank|e<<6, then loc1
  __shared__ unsigned short tk2[NP][T_TOK];  // rank2|e2<<6
  __shared__ float red[64];
  const int tid = threadIdx.x;
  const int wvi = tid >> 6;
  const int p = wvi >> 3;
  const int wg = wvi & 7;            // 8 waves per p, 8 groups of 64 tokens each
  const int l = tid & 63;
  const unsigned long long lmask = (1ull << l) - 1ull;
  // ---- Phase A1: per-group 5-bit match counts + in-group rank ----
  for (int gi = 0; gi < 8; ++gi) {
    const int g = wg * 8 + gi;
    const int t = g * 64 + l;
    const int e1 = idxs[t * 2 + p] & 255;
    if (l < 32) grp[p][g][l] = 0;    // wave-ordered before count store below
    unsigned long long m = ~0ull;
#pragma unroll
    for (int b = 0; b < 5; ++b) {
      const unsigned long long bm = __ballot((e1 >> b) & 1);
      m &= ((e1 >> b) & 1) ? bm : ~bm;
    }
    const int rank = (int)__popcll(m & lmask);
    if (rank == 0) grp[p][g][e1] = (int)__popcll(m);
    tk1[p][t] = (unsigned short)(rank | (e1 << 6));
  }
  __syncthreads();
  // ---- Phase B1: exclusive prefix over 64 groups per (p,e) ----
  if (tid < 64) {
    const int pp = tid >> 5, ee = tid & 31;
    int s = 0;
    for (int g = 0; g < 64; ++g) { int vv = grp[pp][g][ee]; grp[pp][g][ee] = s; s += vv; }
    tot[pp][ee] = s;
  }
  __syncthreads();
  // ---- Phase C1: loc1 per token; l_aux partial per (p,e) ----
  for (int gi = 0; gi < 8; ++gi) {
    const int g = wg * 8 + gi;
    const int t = g * 64 + l;
    const int vv = tk1[p][t];
    tk1[p][t] = (unsigned short)(grp[p][g][vv >> 6] + (vv & 63));
  }
  if (tid < 64) {
    float s = 0.f;
    for (int b = 0; b < 128; ++b) s += me_part[b * 64 + tid];
    red[tid] = s * (float)tot[tid >> 5][tid & 31];   // pre-drop counts
  }
  __syncthreads();  // also protects grp reuse by A2
  if (tid == 0) {
    float s = 0.f;
    for (int i = 0; i < 64; ++i) s += red[i];
    out[0] = s / (64.0f * 4096.0f * 4096.0f);
  }
  // ---- Phase A2: dropped tokens re-pick their top-1 (reference semantics) ----
  for (int gi = 0; gi < 8; ++gi) {
    const int g = wg * 8 + gi;
    const int t = g * 64 + l;
    const int ii = idxs[t * 2 + p];
    const int e2 = (tk1[p][t] < CAP) ? (ii >> 8) : (ii & 255);
    if (l < 32) grp[p][g][l] = 0;
    unsigned long long m = ~0ull;
#pragma unroll
    for (int b = 0; b < 5; ++b) {
      const unsigned long long bm = __ballot((e2 >> b) & 1);
      m &= ((e2 >> b) & 1) ? bm : ~bm;
    }
    const int rank = (int)__popcll(m & lmask);
    if (rank == 0) grp[p][g][e2] = (int)__popcll(m);
    tk2[p][t] = (unsigned short)(rank | (e2 << 6));
  }
  __syncthreads();
  // ---- Phase B2: prefix starting at kept-first-chooser counts ----
  if (tid < 64) {
    const int pp = tid >> 5, ee = tid & 31;
    int s = min(tot[pp][ee], CAP);
    for (int g = 0; g < 64; ++g) { int vv = grp[pp][g][ee]; grp[pp][g][ee] = s; s += vv; }
  }
  __syncthreads();
  // ---- Phase C2: finalize positions + weights ----
  for (int gi = 0; gi < 8; ++gi) {
    const int g = wg * 8 + gi;
    const int t = g * 64 + l;
    const int R = t * 2 + p;
    const int ii = idxs[R];
    const int e1 = ii & 255;
    const int loc1v = tk1[p][t];
    const bool kept1 = loc1v < CAP;
    const int v2 = tk2[p][t];
    const int rank2 = v2 & 63, e2 = v2 >> 6;
    const int loc2 = grp[p][g][e2] + rank2;
    const bool kept2 = loc2 < CAP;
    const float2 gg = g12[R];
    const float gs1 = kept1 ? gg.x : 0.f;
    const float g2v = kept1 ? gg.y : gg.x;
    const float gs2 = kept2 ? g2v : 0.f;
    const float den = fmaxf(gs1 + gs2, 1.1920929e-07f);  // FLT_EPSILON
    fl[R] = make_int2(kept1 ? e1 * CAP + loc1v : -1, kept2 ? e2 * CAP + loc2 : -1);
    wvp[R] = make_float2(gs1 / den, gs2 / den);
  }
}

// ---- writer: ONE contiguous 40KB stream per block (fill-equivalent) ---------
__global__ __launch_bounds__(256) void k_write(const int2* __restrict__ fl,
                                               const float2* __restrict__ wvp,
                                               float* __restrict__ out,
                                               int nfullB) {
  const int b = blockIdx.x;           // 0..4095 combine, 4096..8191 dispatch
  const int tid = threadIdx.x;
  const int region = b >> 12;
  const int bd = b & 4095;            // owns rows 2bd, 2bd+1
  if (region && bd >= nfullB) return; // deferred to tail kernel (scratch overlap)
  int fpos = -1; float fval = 0.f; size_t faddr = 0;
  if (tid < 4) {
    const int rr = 2 * bd + (tid >> 1);
    const int2 f = fl[rr];
    const float2 w = wvp[rr];
    const int which = tid & 1;
    fpos = which ? f.y : f.x;
    fval = region ? 1.0f : (which ? w.y : w.x);
    faddr = 1ull + (region ? COMB_ELEMS : 0ull) + (size_t)rr * 5120 + (size_t)(fpos < 0 ? 0 : fpos);
  }
  const size_t base = 1 + (region ? COMB_ELEMS : 0ull) + (size_t)bd * 10240;  // == 1 mod 4
  float4* p4 = (float4*)(out + base + 3);  // 16B-aligned
  const float4 z4 = make_float4(0.f, 0.f, 0.f, 0.f);
#pragma unroll
  for (int j = 0; j < 10; ++j) {
    const int idx = tid + j * 256;
    if (idx < 2559) p4[idx] = z4;
  }
  if (tid < 3) out[base + tid] = 0.f;
  if (tid == 3) out[base + 10239] = 0.f;
  __syncthreads();
  if (tid < 4 && fpos >= 0) out[faddr] = fval;
}

// tail writer for the all-in-d_out aliasing path: stages fl in LDS first
__global__ __launch_bounds__(1024) void k_write_tail(const int2* __restrict__ fl,
                                                     float* __restrict__ out,
                                                     int nfullB) {
  __shared__ int2 sfl[16];
  const int tid = threadIdx.x;
  const int rstart = nfullB * 2;
  const int nr = 8192 - rstart;      // <= 16
  if (tid < nr) sfl[tid] = fl[rstart + tid];
  __syncthreads();
  const size_t base = 1 + COMB_ELEMS + (size_t)rstart * 5120;  // == 1 mod 4
  const int cnt = nr * 5120;
  const int nx4 = (cnt - 4) >> 2;
  float4* p4 = (float4*)(out + base + 3);
  const float4 z4 = make_float4(0.f, 0.f, 0.f, 0.f);
  for (int idx = tid; idx < nx4; idx += 1024) p4[idx] = z4;
  if (tid < 3) out[base + tid] = 0.f;
  if (tid == 3) out[base + cnt - 1] = 0.f;
  __syncthreads();
  if (tid < 2 * nr) {
    const int rr = rstart + (tid >> 1);
    const int2 f = sfl[tid >> 1];
    const int pos = (tid & 1) ? f.y : f.x;
    if (pos >= 0) out[1 + COMB_ELEMS + (size_t)rr * 5120 + pos] = 1.0f;
  }
}

extern "C" void kernel_launch(void* const* d_in, const int* in_sizes, int n_in,
                              void* d_out, int out_size, void* d_ws, size_t ws_size,
                              hipStream_t stream) {
  const float* x = (const float*)d_in[0];
  const float* W = (const float*)d_in[1];
  float* out = (float*)d_out;

  const size_t PARTF = (size_t)NKC * T_TOK * NE;  // 2,097,152 floats

  float* small;
  float* part;
  int nfullB = 4096;
  if (ws_size >= (SMALLF + PARTF) * sizeof(float)) {
    small = (float*)d_ws;
    part = small + SMALLF;
  } else if (ws_size >= SMALLF * sizeof(float)) {
    small = (float*)d_ws;
    part = out + 4;  // front of combine region, dead before writer runs
  } else {
    // everything inside d_out; scratch at aligned tail; dispatch spans that
    // overlap the scratch are deferred to the single-block tail writer.
    const size_t tb = (OUT_ELEMS - SMALLF) & ~(size_t)3;  // 83820544
    small = out + tb;
    part = out + 4;
    nfullB = (int)((tb - 1 - COMB_ELEMS) / 10240);        // 4089
  }
  float2* g12 = (float2*)small;                 // 16384 floats
  int* idxs = (int*)(small + 16384);            //  8192
  float* me_part = small + 24576;               //  8192
  int2* fl = (int2*)(small + 32768);            // 16384
  float2* wvp = (float2*)(small + 49152);       // 16384  -> total 65536

  hipLaunchKernelGGL(k_gemm, dim3(256), dim3(256), 0, stream, x, W, part);
  hipLaunchKernelGGL(k_soft, dim3(128), dim3(64), 0, stream, part, g12, idxs, me_part);
  hipLaunchKernelGGL(k_scan, dim3(1), dim3(1024), 0, stream, idxs, g12, me_part, fl, wvp, out);
  hipLaunchKernelGGL(k_write, dim3(8192), dim3(256), 0, stream, fl, wvp, out, nfullB);
  if (nfullB < 4096)
    hipLaunchKernelGGL(k_write_tail, dim3(1), dim3(1024), 0, stream, fl, out, nfullB);
}

// Round 7
// 104.015 us; speedup vs baseline: 1.7997x; 1.1858x over previous
//
#include <hip/hip_runtime.h>
#include <cstdint>

#define T_TOK 4096
#define KDIM 2048
#define NE 64
#define NP 2
#define EE 32
#define CAP 160
#define NKC 8
#define KCHUNK 256
#define BLKR 128
#define COMB_ELEMS 41943040ull /* 8192 * 5120 */
#define OUT_ELEMS 83886081ull  /* 1 + 2*COMB */
#define SMALLF 65536           /* floats of small scratch */
#define NFB 4096               /* fill blocks in fused kernel */
#define TOT4 20971520          /* float4s covering OUT_ELEMS-1 */

// ---- fused: blocks 0..255 = GEMM (128r x 64e x 256k), 256.. = zero-fill ----
__global__ __launch_bounds__(256) void k_fused(const float* __restrict__ x,
                                               const float* __restrict__ W,
                                               float* __restrict__ part,
                                               float* __restrict__ out,
                                               int s1lo, int s1hi, int s2lo, int s2hi,
                                               int fillLast) {
  __shared__ float xs[BLKR][36];  // stride 36: 16B-aligned, staggered banks
  __shared__ float wt[32][68];    // [k][e] stride 68
  const int tid = threadIdx.x;
  if (blockIdx.x >= 256) {        // ---------- fill role ----------
    const int fb = blockIdx.x - 256;
    float4* p4 = reinterpret_cast<float4*>(out);
    const float4 z4 = make_float4(0.f, 0.f, 0.f, 0.f);
    const int start = fb * 5120;
#pragma unroll
    for (int j = 0; j < 20; ++j) {
      const int i4 = start + tid + j * 256;
      if (i4 >= s1lo && i4 < s1hi) continue;
      if (i4 >= s2lo && i4 < s2hi) continue;
      p4[i4] = z4;
    }
    if (fillLast && fb == NFB - 1 && tid == 255) out[OUT_ELEMS - 1] = 0.f;
    return;
  }
  // ---------- gemm role (identical math/order to R6) ----------
  const int rb = blockIdx.x & 31;  // 32 row-blocks of 128 rows
  const int kc = blockIdx.x >> 5;  // 8 k-chunks of 256
  const int r0 = rb * BLKR;
  const int er = tid & 15;         // experts er*4 .. +3
  const int rg = tid >> 4;         // rows rg + 16*i, i=0..7
  float acc[8][4];
#pragma unroll
  for (int i = 0; i < 8; ++i)
#pragma unroll
    for (int c = 0; c < 4; ++c) acc[i][c] = 0.f;

  float4 sx[4], sw[2];
  {
    const int kb = kc * KCHUNK;
#pragma unroll
    for (int q = 0; q < 4; ++q) {
      const int li = tid + q * 256, row = li >> 3, kq = (li & 7) * 4;
      sx[q] = *reinterpret_cast<const float4*>(&x[(size_t)(r0 + row) * KDIM + kb + kq]);
    }
#pragma unroll
    for (int q = 0; q < 2; ++q) {
      const int li = tid + q * 256, e = li >> 3, kq = (li & 7) * 4;
      sw[q] = *reinterpret_cast<const float4*>(&W[(size_t)e * KDIM + kb + kq]);
    }
  }
  for (int s = 0; s < 8; ++s) {    // 8 sub-chunks of 32 k
    __syncthreads();
#pragma unroll
    for (int q = 0; q < 4; ++q) {
      const int li = tid + q * 256, row = li >> 3, kq = (li & 7) * 4;
      *reinterpret_cast<float4*>(&xs[row][kq]) = sx[q];
    }
#pragma unroll
    for (int q = 0; q < 2; ++q) {
      const int li = tid + q * 256, e = li >> 3, kq = (li & 7) * 4;
      wt[kq][e] = sw[q].x; wt[kq + 1][e] = sw[q].y;
      wt[kq + 2][e] = sw[q].z; wt[kq + 3][e] = sw[q].w;
    }
    if (s < 7) {                   // prefetch s+1 under compute(s)
      const int kb = kc * KCHUNK + (s + 1) * 32;
#pragma unroll
      for (int q = 0; q < 4; ++q) {
        const int li = tid + q * 256, row = li >> 3, kq = (li & 7) * 4;
        sx[q] = *reinterpret_cast<const float4*>(&x[(size_t)(r0 + row) * KDIM + kb + kq]);
      }
#pragma unroll
      for (int q = 0; q < 2; ++q) {
        const int li = tid + q * 256, e = li >> 3, kq = (li & 7) * 4;
        sw[q] = *reinterpret_cast<const float4*>(&W[(size_t)e * KDIM + kb + kq]);
      }
    }
    __syncthreads();
#pragma unroll
    for (int k4 = 0; k4 < 8; ++k4) {
      float4 wb[4];
#pragma unroll
      for (int j = 0; j < 4; ++j)
        wb[j] = *reinterpret_cast<const float4*>(&wt[k4 * 4 + j][er * 4]);
#pragma unroll
      for (int i = 0; i < 8; ++i) {
        const float4 xv = *reinterpret_cast<const float4*>(&xs[rg + 16 * i][k4 * 4]);
        // k ascending nested fmaf: bitwise-identical accumulation to R5/R6
        acc[i][0] = fmaf(xv.w, wb[3].x, fmaf(xv.z, wb[2].x, fmaf(xv.y, wb[1].x, fmaf(xv.x, wb[0].x, acc[i][0]))));
        acc[i][1] = fmaf(xv.w, wb[3].y, fmaf(xv.z, wb[2].y, fmaf(xv.y, wb[1].y, fmaf(xv.x, wb[0].y, acc[i][1]))));
        acc[i][2] = fmaf(xv.w, wb[3].z, fmaf(xv.z, wb[2].z, fmaf(xv.y, wb[1].z, fmaf(xv.x, wb[0].z, acc[i][2]))));
        acc[i][3] = fmaf(xv.w, wb[3].w, fmaf(xv.z, wb[2].w, fmaf(xv.y, wb[1].w, fmaf(xv.x, wb[0].w, acc[i][3]))));
      }
    }
  }
#pragma unroll
  for (int i = 0; i < 8; ++i) {
    float4 v; v.x = acc[i][0]; v.y = acc[i][1]; v.z = acc[i][2]; v.w = acc[i][3];
    *reinterpret_cast<float4*>(
        &part[((size_t)kc * T_TOK + r0 + rg + 16 * i) * NE + er * 4]) = v;
  }
}

// zero the part span [4, 4+PARTF) after k_soft consumed it (aliasing paths)
__global__ __launch_bounds__(256) void k_fill2(float* __restrict__ out) {
  float4* p4 = reinterpret_cast<float4*>(out + 4);
  const float4 z4 = make_float4(0.f, 0.f, 0.f, 0.f);
  const int base = blockIdx.x * 2048 + threadIdx.x;
#pragma unroll
  for (int j = 0; j < 8; ++j) p4[base + j * 256] = z4;
}

// ------------- softmax + top2 candidates + l_aux me partials ------------------
__global__ __launch_bounds__(64) void k_soft(const float* __restrict__ part,
                                             float2* __restrict__ g12,
                                             int* __restrict__ idxs,
                                             float* __restrict__ me_part) {
  __shared__ float lg[64][33];
  const int tid = threadIdx.x;
  const int R = blockIdx.x * 64 + tid;  // R = t*2 + p
  const int t = R >> 1;
  const int p = R & 1;
  float v[32];
  const float* pr = part + (size_t)t * NE + p * EE;
#pragma unroll
  for (int e = 0; e < 32; e += 4) {
    float4 s = *reinterpret_cast<const float4*>(pr + e);
    v[e] = s.x; v[e + 1] = s.y; v[e + 2] = s.z; v[e + 3] = s.w;
  }
  for (int kc = 1; kc < NKC; ++kc) {
    const float* prk = pr + (size_t)kc * T_TOK * NE;
#pragma unroll
    for (int e = 0; e < 32; e += 4) {
      float4 s = *reinterpret_cast<const float4*>(prk + e);
      v[e] += s.x; v[e + 1] += s.y; v[e + 2] += s.z; v[e + 3] += s.w;
    }
  }
  float m = v[0];
#pragma unroll
  for (int e = 1; e < 32; ++e) m = fmaxf(m, v[e]);
  float sum = 0.f;
#pragma unroll
  for (int e = 0; e < 32; ++e) { v[e] = expf(v[e] - m); sum += v[e]; }
  const float inv = 1.0f / sum;
#pragma unroll
  for (int e = 0; e < 32; ++e) v[e] *= inv;
  float g1 = -1.f; int i1 = 0;
#pragma unroll
  for (int e = 0; e < 32; ++e) if (v[e] > g1) { g1 = v[e]; i1 = e; }  // first-max, like jnp.argmax
  float g2 = -1.f; int i2 = 0;
#pragma unroll
  for (int e = 0; e < 32; ++e) if (e != i1 && v[e] > g2) { g2 = v[e]; i2 = e; }
  g12[R] = make_float2(g1, g2);
  idxs[R] = i1 | (i2 << 8);
#pragma unroll
  for (int e = 0; e < 32; ++e) lg[tid][e] = v[e];
  __syncthreads();
  {
    const int pp = tid >> 5, ee = tid & 31;
    float s = 0.f;
    for (int rr = pp; rr < 64; rr += 2) s += lg[rr][ee];
    me_part[blockIdx.x * 64 + tid] = s;
  }
}

// ------- hierarchical ordered scans, 5-bit match trick -----------------------
__global__ __launch_bounds__(1024) void k_scan(const int* __restrict__ idxs,
                                               const float2* __restrict__ g12,
                                               const float* __restrict__ me_part,
                                               int2* __restrict__ fl,
                                               float2* __restrict__ wvp,
                                               float* __restrict__ out) {
  __shared__ int grp[NP][64][32];
  __shared__ int tot[NP][32];
  __shared__ unsigned short tk1[NP][T_TOK];
  __shared__ unsigned short tk2[NP][T_TOK];
  __shared__ float red[64];
  const int tid = threadIdx.x;
  const int wvi = tid >> 6;
  const int p = wvi >> 3;
  const int wg = wvi & 7;
  const int l = tid & 63;
  const unsigned long long lmask = (1ull << l) - 1ull;
  for (int gi = 0; gi < 8; ++gi) {
    const int g = wg * 8 + gi;
    const int t = g * 64 + l;
    const int e1 = idxs[t * 2 + p] & 255;
    if (l < 32) grp[p][g][l] = 0;
    unsigned long long m = ~0ull;
#pragma unroll
    for (int b = 0; b < 5; ++b) {
      const unsigned long long bm = __ballot((e1 >> b) & 1);
      m &= ((e1 >> b) & 1) ? bm : ~bm;
    }
    const int rank = (int)__popcll(m & lmask);
    if (rank == 0) grp[p][g][e1] = (int)__popcll(m);
    tk1[p][t] = (unsigned short)(rank | (e1 << 6));
  }
  __syncthreads();
  if (tid < 64) {
    const int pp = tid >> 5, ee = tid & 31;
    int s = 0;
    for (int g = 0; g < 64; ++g) { int vv = grp[pp][g][ee]; grp[pp][g][ee] = s; s += vv; }
    tot[pp][ee] = s;
  }
  __syncthreads();
  for (int gi = 0; gi < 8; ++gi) {
    const int g = wg * 8 + gi;
    const int t = g * 64 + l;
    const int vv = tk1[p][t];
    tk1[p][t] = (unsigned short)(grp[p][g][vv >> 6] + (vv & 63));
  }
  if (tid < 64) {
    float s = 0.f;
    for (int b = 0; b < 128; ++b) s += me_part[b * 64 + tid];
    red[tid] = s * (float)tot[tid >> 5][tid & 31];
  }
  __syncthreads();
  if (tid == 0) {
    float s = 0.f;
    for (int i = 0; i < 64; ++i) s += red[i];
    out[0] = s / (64.0f * 4096.0f * 4096.0f);
  }
  for (int gi = 0; gi < 8; ++gi) {
    const int g = wg * 8 + gi;
    const int t = g * 64 + l;
    const int ii = idxs[t * 2 + p];
    const int e2 = (tk1[p][t] < CAP) ? (ii >> 8) : (ii & 255);
    if (l < 32) grp[p][g][l] = 0;
    unsigned long long m = ~0ull;
#pragma unroll
    for (int b = 0; b < 5; ++b) {
      const unsigned long long bm = __ballot((e2 >> b) & 1);
      m &= ((e2 >> b) & 1) ? bm : ~bm;
    }
    const int rank = (int)__popcll(m & lmask);
    if (rank == 0) grp[p][g][e2] = (int)__popcll(m);
    tk2[p][t] = (unsigned short)(rank | (e2 << 6));
  }
  __syncthreads();
  if (tid < 64) {
    const int pp = tid >> 5, ee = tid & 31;
    int s = min(tot[pp][ee], CAP);
    for (int g = 0; g < 64; ++g) { int vv = grp[pp][g][ee]; grp[pp][g][ee] = s; s += vv; }
  }
  __syncthreads();
  for (int gi = 0; gi < 8; ++gi) {
    const int g = wg * 8 + gi;
    const int t = g * 64 + l;
    const int R = t * 2 + p;
    const int ii = idxs[R];
    const int e1 = ii & 255;
    const int loc1v = tk1[p][t];
    const bool kept1 = loc1v < CAP;
    const int v2 = tk2[p][t];
    const int rank2 = v2 & 63, e2 = v2 >> 6;
    const int loc2 = grp[p][g][e2] + rank2;
    const bool kept2 = loc2 < CAP;
    const float2 gg = g12[R];
    const float gs1 = kept1 ? gg.x : 0.f;
    const float g2v = kept1 ? gg.y : gg.x;
    const float gs2 = kept2 ? g2v : 0.f;
    const float den = fmaxf(gs1 + gs2, 1.1920929e-07f);  // FLT_EPSILON
    fl[R] = make_int2(kept1 ? e1 * CAP + loc1v : -1, kept2 ? e2 * CAP + loc2 : -1);
    wvp[R] = make_float2(gs1 / den, gs2 / den);
  }
}

// ---- point-fix: scatter the <=4 nonzeros per row into zeroed output ---------
__global__ __launch_bounds__(256) void k_fix(const int2* __restrict__ fl,
                                             const float2* __restrict__ wvp,
                                             float* __restrict__ out,
                                             int rlimit) {
  const int R = blockIdx.x * 256 + threadIdx.x;  // 0..8191
  const int2 f = fl[R];
  const float2 w = wvp[R];
  float* oc = out + 1 + (size_t)R * 5120;
  if (f.x >= 0) oc[f.x] = w.x;
  if (f.y >= 0) oc[f.y] = w.y;
  if (R < rlimit) {
    float* od = out + 1 + COMB_ELEMS + (size_t)R * 5120;
    if (f.x >= 0) od[f.x] = 1.0f;
    if (f.y >= 0) od[f.y] = 1.0f;
  }
}

// tail writer (aliasing path): zero scratch region of dispatch + its fixes
__global__ __launch_bounds__(1024) void k_write_tail(const int2* __restrict__ fl,
                                                     float* __restrict__ out,
                                                     int nfullB) {
  __shared__ int2 sfl[16];
  const int tid = threadIdx.x;
  const int rstart = nfullB * 2;
  const int nr = 8192 - rstart;      // <= 16
  if (tid < nr) sfl[tid] = fl[rstart + tid];
  __syncthreads();
  const size_t base = 1 + COMB_ELEMS + (size_t)rstart * 5120;  // == 1 mod 4
  const int cnt = nr * 5120;
  const int nx4 = (cnt - 4) >> 2;
  float4* p4 = (float4*)(out + base + 3);
  const float4 z4 = make_float4(0.f, 0.f, 0.f, 0.f);
  for (int idx = tid; idx < nx4; idx += 1024) p4[idx] = z4;
  if (tid < 3) out[base + tid] = 0.f;
  if (tid == 3) out[base + cnt - 1] = 0.f;
  __syncthreads();
  if (tid < 2 * nr) {
    const int rr = rstart + (tid >> 1);
    const int2 f = sfl[tid >> 1];
    const int pos = (tid & 1) ? f.y : f.x;
    if (pos >= 0) out[1 + COMB_ELEMS + (size_t)rr * 5120 + pos] = 1.0f;
  }
}

extern "C" void kernel_launch(void* const* d_in, const int* in_sizes, int n_in,
                              void* d_out, int out_size, void* d_ws, size_t ws_size,
                              hipStream_t stream) {
  const float* x = (const float*)d_in[0];
  const float* W = (const float*)d_in[1];
  float* out = (float*)d_out;

  const size_t PARTF = (size_t)NKC * T_TOK * NE;  // 2,097,152 floats

  float* small;
  float* part;
  int s1lo = 0, s1hi = 0, s2lo = 0, s2hi = 0, fillLast = 1;
  bool needFill2 = false;
  int nfullB = 4096, rlimit = 8192;
  if (ws_size >= (SMALLF + PARTF) * sizeof(float)) {
    small = (float*)d_ws;
    part = small + SMALLF;
  } else if (ws_size >= SMALLF * sizeof(float)) {
    small = (float*)d_ws;
    part = out + 4;                       // inside combine; fill skips, fill2 re-zeroes
    s1lo = 1; s1hi = 1 + (int)(PARTF / 4);
    needFill2 = true;
  } else {
    const size_t tb = (OUT_ELEMS - SMALLF) & ~(size_t)3;  // 83820544
    small = out + tb;
    part = out + 4;
    s1lo = 1; s1hi = 1 + (int)(PARTF / 4);
    s2lo = (int)(tb / 4); s2hi = TOT4;
    fillLast = 0;
    needFill2 = true;
    nfullB = (int)((tb - 1 - COMB_ELEMS) / 10240);        // 4089
    rlimit = nfullB * 2;
  }
  float2* g12 = (float2*)small;                 // 16384 floats
  int* idxs = (int*)(small + 16384);            //  8192
  float* me_part = small + 24576;               //  8192
  int2* fl = (int2*)(small + 32768);            // 16384
  float2* wvp = (float2*)(small + 49152);       // 16384  -> total 65536

  hipLaunchKernelGGL(k_fused, dim3(256 + NFB), dim3(256), 0, stream,
                     x, W, part, out, s1lo, s1hi, s2lo, s2hi, fillLast);
  hipLaunchKernelGGL(k_soft, dim3(128), dim3(64), 0, stream, part, g12, idxs, me_part);
  if (needFill2)
    hipLaunchKernelGGL(k_fill2, dim3(256), dim3(256), 0, stream, out);
  hipLaunchKernelGGL(k_scan, dim3(1), dim3(1024), 0, stream, idxs, g12, me_part, fl, wvp, out);
  hipLaunchKernelGGL(k_fix, dim3(32), dim3(256), 0, stream, fl, wvp, out, rlimit);
  if (nfullB < 4096)
    hipLaunchKernelGGL(k_write_tail, dim3(1), dim3(1024), 0, stream, fl, out, nfullB);
}